// Round 21
// baseline (168.626 us; speedup 1.0000x reference)
//
#include <hip/hip_runtime.h>
#include <hip/hip_fp8.h>

// GAT 2-layer. N=50000, E=1.6M (deg 32). L1: 256->8x32 (bf16 MFMA).
// feat stored FP8 e4m3; agg1: 8-edge groups, readlane SGPR row base,
// cvt_pk + packed-fma, (off,deg) int2. gemm1m: LDS-staged A, 4 waves x
// 64-col, walar el/er chain. CSR: cap-strided single-pass partition
// (LDS sort + atomic-return bucket reservation) -> per-bucket LDS sort.
// agg2: 16-lane quarter-wave per node.

#define NN 50000
#define NE 1600000
#define NBK 196      // coarse buckets of 256 nodes
#define NPB 1024     // partition blocks
#define PCH 1563     // edges per partition block; 1024*1563 >= NE
#define CAP 16384    // stage/csr slots per bucket (mean 8192, ~90 sigma)

typedef __attribute__((ext_vector_type(8))) short short8;
typedef __attribute__((ext_vector_type(4))) float f32x4;
typedef __attribute__((ext_vector_type(2))) float f32x2;

__device__ inline unsigned short f2bf(float f) {
  unsigned int u = __float_as_uint(f);
  unsigned int r = (u + 0x7fffu + ((u >> 16) & 1u)) >> 16;
  return (unsigned short)r;
}
__device__ inline unsigned char f2fp8(float f) {
  __hip_fp8_e4m3 q(f);
  return *reinterpret_cast<unsigned char*>(&q);
}
__device__ inline float lrelu_exp(float v) {
  v = v >= 0.f ? v : 0.2f * v;
  return __expf(v);
}

// single-pass partition: LDS hist (dst stashed) -> LDS scan -> atomic-return
// bucket reservation -> LDS sort -> coalesced cap-strided copy-out.
// Entry = (bucket<<24)|((dst&255)<<16)|src. cur accumulates bucket totals.
__global__ __launch_bounds__(256) void k_part(const int* __restrict__ dst,
                                              const int* __restrict__ src,
                                              int* __restrict__ cur,
                                              int* __restrict__ stage, int E) {
  __shared__ int sbuf[PCH];
  __shared__ int dbuf[PCH];
  __shared__ int h[NBK], scn[NBK], base[NBK], lofs[NBK];
  __shared__ int sc[256];
  int tid = threadIdx.x, blk = blockIdx.x;
  for (int i = tid; i < NBK; i += 256) { h[i] = 0; lofs[i] = 0; }
  __syncthreads();
  int b0 = blk * PCH;
  int tot = min(PCH, E - b0);
  for (int k = tid; k < tot; k += 256) {
    int d = dst[b0 + k];
    dbuf[k] = d;
    atomicAdd(&h[d >> 8], 1);
  }
  __syncthreads();
  int v = (tid < NBK) ? h[tid] : 0;
  sc[tid] = v;
  __syncthreads();
  for (int off = 1; off < 256; off <<= 1) {
    int t = (tid >= off) ? sc[tid - off] : 0;
    __syncthreads();
    sc[tid] += t;
    __syncthreads();
  }
  if (tid < NBK) {
    scn[tid] = sc[tid] - v;
    base[tid] = v ? atomicAdd(&cur[tid], v) : 0;
  }
  __syncthreads();
  for (int k = tid; k < tot; k += 256) {
    int d = dbuf[k];
    int b = d >> 8;
    int r = atomicAdd(&lofs[b], 1);
    sbuf[scn[b] + r] = (b << 24) | ((d & 255) << 16) | src[b0 + k];
  }
  __syncthreads();
  for (int i = tid; i < tot; i += 256) {
    int e = sbuf[i];
    int b = (unsigned)e >> 24;
    stage[(size_t)b * CAP + base[b] + (i - scn[b])] = e;
  }
}

// per-bucket LDS counting sort: od (int2: cap-strided off, deg) + csr.
__global__ __launch_bounds__(512) void k_build(const int* __restrict__ stage,
                                               const int* __restrict__ tots,
                                               int2* __restrict__ od,
                                               unsigned short* __restrict__ csr,
                                               int n) {
  __shared__ int h[256], buf[256], cur[256];
  int b = blockIdx.x, tid = threadIdx.x;
  int tot = tots[b];
  const int* st = stage + (size_t)b * CAP;
  unsigned short* cs = csr + (size_t)b * CAP;
  if (tid < 256) h[tid] = 0;
  __syncthreads();
  for (int k = tid; k < tot; k += 512)
    atomicAdd(&h[(st[k] >> 16) & 255], 1);
  __syncthreads();
  int v = (tid < 256) ? h[tid] : 0;
  if (tid < 256) buf[tid] = v;
  __syncthreads();
  for (int off = 1; off < 256; off <<= 1) {
    int t = (tid >= off && tid < 256) ? buf[tid - off] : 0;
    __syncthreads();
    if (tid < 256) buf[tid] += t;
    __syncthreads();
  }
  if (tid < 256) {
    int excl = buf[tid] - v;
    int node = b * 256 + tid;
    if (node < n) od[node] = make_int2(b * CAP + excl, v);
    cur[tid] = excl;
  }
  __syncthreads();
  for (int k = tid; k < tot; k += 512) {
    int p = st[k];
    int r = atomicAdd(&cur[(p >> 16) & 255], 1);
    cs[r] = (unsigned short)(p & 0xFFFF);
  }
}

// Pack W1 into MFMA B-fragment order (bf16) + walar = W1@[Ael|Aer] fragments.
__global__ __launch_bounds__(256) void k_packw(const float* __restrict__ W1,
                                               const float* __restrict__ al,
                                               const float* __restrict__ ar,
                                               unsigned short* __restrict__ W1p,
                                               unsigned short* __restrict__ walar) {
  int idx = blockIdx.x * 256 + threadIdx.x;
  if (idx < 8192) {  // W1p
    int nf = idx >> 9, rem = idx & 511;
    int ks = rem >> 6, lane = rem & 63;
    int n = nf * 16 + (lane & 15);
    int kb = ks * 32 + (lane >> 4) * 8;
#pragma unroll
    for (int j = 0; j < 8; ++j)
      W1p[(size_t)idx * 8 + j] = f2bf(W1[(kb + j) * 256 + n]);
  } else if (idx < 8192 + 512) {  // walar: [ks][lane] frag of 256x16
    int idx2 = idx - 8192;
    int ks = idx2 >> 6, lane = idx2 & 63;
    int n = lane & 15;
    int kb = ks * 32 + (lane >> 4) * 8;
    const float* coef = (n < 8) ? (al + n * 32) : (ar + (n - 8) * 32);
    int bc = (n < 8) ? n * 32 : (n - 8) * 32;
#pragma unroll
    for (int j = 0; j < 8; ++j) {
      int k = kb + j;
      float s = 0.f;
      for (int f = 0; f < 32; ++f) s += W1[k * 256 + bc + f] * coef[f];
      walar[(size_t)idx2 * 8 + j] = f2bf(s);
    }
  }
}

// MFMA GEMM, column-split + LDS-staged A: block = 32-row tile converted to
// bf16 in LDS once; wave w handles nf group {4w..4w+3}. Wave 0 adds walar.
__global__ __launch_bounds__(256) void k_gemm1m(
    const float* __restrict__ x, const unsigned short* __restrict__ W1p,
    const unsigned short* __restrict__ walar,
    unsigned char* __restrict__ feat8, float* __restrict__ el,
    float* __restrict__ er, int n) {
  __shared__ unsigned short xs[32][264];  // row stride 528B = 33x16B
  int w = threadIdx.x >> 6, lane = threadIdx.x & 63;
  int tile = blockIdx.x * 32;
  if (tile >= n) return;
  for (int idx = threadIdx.x; idx < 2048; idx += 256) {
    int r = idx >> 6, c4 = (idx & 63) * 4;
    int row = tile + r;
    float4 v = (row < n)
                   ? *reinterpret_cast<const float4*>(x + (size_t)row * 256 + c4)
                   : make_float4(0.f, 0.f, 0.f, 0.f);
    xs[r][c4 + 0] = f2bf(v.x);
    xs[r][c4 + 1] = f2bf(v.y);
    xs[r][c4 + 2] = f2bf(v.z);
    xs[r][c4 + 3] = f2bf(v.w);
  }
  __syncthreads();
  int r0 = lane & 15, kgrp = lane >> 4;
  int nf0 = w * 4;
  f32x4 acc[4][2];
  f32x4 accE[2];
#pragma unroll
  for (int nf = 0; nf < 4; ++nf)
#pragma unroll
    for (int mf = 0; mf < 2; ++mf) acc[nf][mf] = (f32x4){0.f, 0.f, 0.f, 0.f};
  accE[0] = (f32x4){0.f, 0.f, 0.f, 0.f};
  accE[1] = (f32x4){0.f, 0.f, 0.f, 0.f};

  for (int ks = 0; ks < 8; ++ks) {
    int kb = ks * 32 + kgrp * 8;
    short8 a0 = *reinterpret_cast<const short8*>(&xs[r0][kb]);
    short8 a1 = *reinterpret_cast<const short8*>(&xs[16 + r0][kb]);
#pragma unroll
    for (int nf = 0; nf < 4; ++nf) {
      short8 b = *reinterpret_cast<const short8*>(
          W1p + ((size_t)((nf0 + nf) * 8 + ks) * 64 + lane) * 8);
      acc[nf][0] = __builtin_amdgcn_mfma_f32_16x16x32_bf16(a0, b, acc[nf][0], 0, 0, 0);
      acc[nf][1] = __builtin_amdgcn_mfma_f32_16x16x32_bf16(a1, b, acc[nf][1], 0, 0, 0);
    }
    if (w == 0) {
      short8 bE = *reinterpret_cast<const short8*>(
          walar + ((size_t)ks * 64 + lane) * 8);
      accE[0] = __builtin_amdgcn_mfma_f32_16x16x32_bf16(a0, bE, accE[0], 0, 0, 0);
      accE[1] = __builtin_amdgcn_mfma_f32_16x16x32_bf16(a1, bE, accE[1], 0, 0, 0);
    }
  }
  // store feat fp8
#pragma unroll
  for (int nf = 0; nf < 4; ++nf)
#pragma unroll
    for (int mf = 0; mf < 2; ++mf)
#pragma unroll
      for (int q = 0; q < 4; ++q) {
        int row = tile + mf * 16 + kgrp * 4 + q;
        if (row < n)
          feat8[(size_t)row * 256 + (nf0 + nf) * 16 + r0] = f2fp8(acc[nf][mf][q]);
      }
  // store el/er (wave 0): D col c=r0 (c<8 -> el head c, else er head c-8)
  if (w == 0) {
#pragma unroll
    for (int mf = 0; mf < 2; ++mf)
#pragma unroll
      for (int q = 0; q < 4; ++q) {
        int row = tile + mf * 16 + kgrp * 4 + q;
        if (row < n) {
          if (r0 < 8) el[(size_t)row * 8 + r0] = accE[mf][q];
          else        er[(size_t)row * 8 + (r0 - 8)] = accE[mf][q];
        }
      }
  }
}

// Wave per dst node. Lane l owns cols l*4..l*4+3 (head hh=l>>3).
// 8-edge groups: lane (e=l>>3, h=l&7) computes ee once. s via readlane
// (SGPR row base); packed fma on cvt_pk outputs. (off,deg) = one int2 load.
__global__ __launch_bounds__(256) void k_agg1(
    const unsigned char* __restrict__ feat8, const float* __restrict__ el,
    const float* __restrict__ er, const int2* __restrict__ od,
    const unsigned short* __restrict__ csr, const float* __restrict__ b1,
    const float* __restrict__ W2, const float* __restrict__ al2,
    const float* __restrict__ ar2, float4* __restrict__ node4, int n) {
  int dn = blockIdx.x * 4 + (threadIdx.x >> 6);
  if (dn >= n) return;
  int l = threadIdx.x & 63;
  int hh = l >> 3;
  int h8 = l & 7;
  float erv = er[dn * 8 + h8];
  int2 o2 = od[dn];
  int beg = o2.x, end = o2.x + o2.y;
  f32x2 acc01 = {0.f, 0.f}, acc23 = {0.f, 0.f};
  float den = 0.f;
  int g = beg;
  for (; g + 8 <= end; g += 8) {
    int s_my = csr[g + (l >> 3)];
    float eev = lrelu_exp(el[s_my * 8 + h8] + erv);
#pragma unroll
    for (int e = 0; e < 8; ++e) {
      int s = __builtin_amdgcn_readlane(s_my, e * 8);  // uniform -> SGPR
      float ee = __shfl(eev, e * 8 + hh, 64);
      den += ee;
      const unsigned char* rowp = feat8 + (size_t)s * 256;  // scalar base
      unsigned int fv = *reinterpret_cast<const unsigned int*>(rowp + l * 4);
      f32x2 lo = __builtin_amdgcn_cvt_pk_f32_fp8(fv, false);
      f32x2 hi = __builtin_amdgcn_cvt_pk_f32_fp8(fv, true);
      f32x2 ee2 = {ee, ee};
      acc01 = ee2 * lo + acc01;
      acc23 = ee2 * hi + acc23;
    }
  }
  if (g < end) {
    int rem = end - g;
    int idx = g + (l >> 3);
    int s_t = csr[idx < end ? idx : end - 1];
    float ee_t = lrelu_exp(el[s_t * 8 + h8] + erv);
    for (int e = 0; e < rem; ++e) {
      int s = __builtin_amdgcn_readlane(s_t, e * 8);
      float ee = __shfl(ee_t, e * 8 + hh, 64);
      den += ee;
      const unsigned char* rowp = feat8 + (size_t)s * 256;
      unsigned int fv = *reinterpret_cast<const unsigned int*>(rowp + l * 4);
      f32x2 lo = __builtin_amdgcn_cvt_pk_f32_fp8(fv, false);
      f32x2 hi = __builtin_amdgcn_cvt_pk_f32_fp8(fv, true);
      f32x2 ee2 = {ee, ee};
      acc01 = ee2 * lo + acc01;
      acc23 = ee2 * hi + acc23;
    }
  }
  float4 bv = *reinterpret_cast<const float4*>(b1 + l * 4);
  float4 w2e = *reinterpret_cast<const float4*>(W2 + l * 8);
  float4 w2o = *reinterpret_cast<const float4*>(W2 + l * 8 + 4);
  float inv = 1.f / fmaxf(den, 1e-16f);
  float v0 = acc01[0] * inv + bv.x; v0 = v0 > 0.f ? v0 : expm1f(v0);
  float v1 = acc01[1] * inv + bv.y; v1 = v1 > 0.f ? v1 : expm1f(v1);
  float v2 = acc23[0] * inv + bv.z; v2 = v2 > 0.f ? v2 : expm1f(v2);
  float v3 = acc23[1] * inv + bv.w; v3 = v3 > 0.f ? v3 : expm1f(v3);
  float p0 = v0 * w2e.x + v1 * w2e.z + v2 * w2o.x + v3 * w2o.z;
  float p1 = v0 * w2e.y + v1 * w2e.w + v2 * w2o.y + v3 * w2o.w;
#pragma unroll
  for (int off = 32; off; off >>= 1) {
    p0 += __shfl_xor(p0, off, 64);
    p1 += __shfl_xor(p1, off, 64);
  }
  if (l == 0) {
    float e2 = p0 * al2[0] + p1 * al2[1];
    float r2 = p0 * ar2[0] + p1 * ar2[1];
    node4[dn] = make_float4(p0, p1, e2, r2);
  }
}

// 16-lane quarter-wave per node; float4 gather/edge; fused log_softmax.
__global__ __launch_bounds__(256) void k_agg2(
    const float4* __restrict__ node4, const int2* __restrict__ od,
    const unsigned short* __restrict__ csr, const float* __restrict__ b2,
    float* __restrict__ out, int n) {
  int dn = blockIdx.x * 16 + (threadIdx.x >> 4);
  int l = threadIdx.x & 15;
  if (dn >= n) return;
  float erd = node4[dn].w;
  int2 o2 = od[dn];
  int beg = o2.x, end = o2.x + o2.y;
  float den = 0.f, a0 = 0.f, a1 = 0.f;
  for (int e = beg + l; e < end; e += 16) {
    int s = csr[e];
    float4 n4 = node4[s];
    float ev = n4.z + erd;
    ev = ev >= 0.f ? ev : 0.2f * ev;
    float ee = __expf(ev);
    den += ee;
    a0 = fmaf(ee, n4.x, a0);
    a1 = fmaf(ee, n4.y, a1);
  }
#pragma unroll
  for (int off = 8; off; off >>= 1) {
    den += __shfl_xor(den, off, 16);
    a0 += __shfl_xor(a0, off, 16);
    a1 += __shfl_xor(a1, off, 16);
  }
  if (l == 0) {
    float inv = 1.f / fmaxf(den, 1e-16f);
    float z0 = a0 * inv + b2[0];
    float z1 = a1 * inv + b2[1];
    float m = fmaxf(z0, z1);
    float lse = m + logf(__expf(z0 - m) + __expf(z1 - m));
    out[dn * 2 + 0] = z0 - lse;
    out[dn * 2 + 1] = z1 - lse;
  }
}

extern "C" void kernel_launch(void* const* d_in, const int* in_sizes, int n_in,
                              void* d_out, int out_size, void* d_ws,
                              size_t ws_size, hipStream_t stream) {
  const float* x   = (const float*)d_in[0];
  const int* esrc  = (const int*)d_in[1];
  const int* edst  = (const int*)d_in[2];
  const float* W1  = (const float*)d_in[3];
  const float* al1 = (const float*)d_in[4];
  const float* ar1 = (const float*)d_in[5];
  const float* b1  = (const float*)d_in[6];
  const float* W2  = (const float*)d_in[7];
  const float* al2 = (const float*)d_in[8];
  const float* ar2 = (const float*)d_in[9];
  const float* b2  = (const float*)d_in[10];
  float* out = (float*)d_out;

  size_t off = 0;
  auto alloc = [&](size_t bytes) {
    void* p = (char*)d_ws + off;
    off += (bytes + 255) & ~(size_t)255;
    return p;
  };
  unsigned char* feat8 = (unsigned char*)alloc((size_t)NN * 256);
  unsigned short* W1p  = (unsigned short*)alloc((size_t)16 * 8 * 64 * 8 * 2);
  unsigned short* walar = (unsigned short*)alloc((size_t)8 * 64 * 8 * 2);
  float* el1    = (float*)alloc((size_t)NN * 8 * 4);
  float* er1    = (float*)alloc((size_t)NN * 8 * 4);
  float4* node4 = (float4*)alloc((size_t)NN * 16);
  int* stage    = (int*)alloc((size_t)NBK * CAP * 4);
  unsigned short* csr = (unsigned short*)alloc((size_t)NBK * CAP * 2);
  int2* od      = (int2*)alloc((size_t)NN * 8);
  int* cur      = (int*)alloc((size_t)NBK * 4);

  hipMemsetAsync(cur, 0, (size_t)NBK * 4, stream);
  k_part<<<NPB, 256, 0, stream>>>(edst, esrc, cur, stage, NE);
  k_build<<<NBK, 512, 0, stream>>>(stage, cur, od, csr, NN);

  k_packw<<<34, 256, 0, stream>>>(W1, al1, ar1, W1p, walar);
  k_gemm1m<<<(NN + 31) / 32, 256, 0, stream>>>(x, W1p, walar, feat8, el1,
                                               er1, NN);
  k_agg1<<<(NN + 3) / 4, 256, 0, stream>>>(feat8, el1, er1, od, csr, b1,
                                           W2, al2, ar2, node4, NN);
  k_agg2<<<(NN + 15) / 16, 256, 0, stream>>>(node4, od, csr, b2, out, NN);
}

// Round 22
// 154.044 us; speedup vs baseline: 1.0947x; 1.0947x over previous
//
#include <hip/hip_runtime.h>
#include <hip/hip_fp8.h>

// GAT 2-layer. N=50000, E=1.6M (deg 32). L1: 256->8x32 (bf16 MFMA).
// feat stored FP8 e4m3; agg1: 8-edge groups, readlane SGPR row base,
// cvt_pk + packed-fma, (off,deg) int2. gemm1m: LDS-staged A, 4 waves x
// 64-col, walar el/er chain. CSR: cap-strided, atomic-free 2-pass
// partition (hist-matrix + column scan) -> per-bucket LDS sort.
// agg2: 16-lane quarter-wave per node.  [round-20 configuration, best]

#define NN 50000
#define NE 1600000
#define NBK 196      // coarse buckets of 256 nodes
#define NPB 1024     // partition blocks
#define PCH 1563     // edges per partition block; 1024*1563 >= NE
#define CAP 16384    // stage/csr slots per bucket (mean 8192, ~90 sigma)

typedef __attribute__((ext_vector_type(8))) short short8;
typedef __attribute__((ext_vector_type(4))) float f32x4;
typedef __attribute__((ext_vector_type(2))) float f32x2;

__device__ inline unsigned short f2bf(float f) {
  unsigned int u = __float_as_uint(f);
  unsigned int r = (u + 0x7fffu + ((u >> 16) & 1u)) >> 16;
  return (unsigned short)r;
}
__device__ inline unsigned char f2fp8(float f) {
  __hip_fp8_e4m3 q(f);
  return *reinterpret_cast<unsigned char*>(&q);
}
__device__ inline float lrelu_exp(float v) {
  v = v >= 0.f ? v : 0.2f * v;
  return __expf(v);
}

// pass 1: per-block LDS hist -> hmat[bucket][block].
__global__ __launch_bounds__(256) void k_hist2(const int* __restrict__ dst,
                                               int* __restrict__ hmat, int E) {
  __shared__ int h[NBK];
  int tid = threadIdx.x, blk = blockIdx.x;
  for (int i = tid; i < NBK; i += 256) h[i] = 0;
  __syncthreads();
  int b0 = blk * PCH;
  int tot = min(PCH, E - b0);
  for (int k = tid; k < tot; k += 256)
    atomicAdd(&h[dst[b0 + k] >> 8], 1);
  __syncthreads();
  for (int i = tid; i < NBK; i += 256)
    hmat[(size_t)i * NPB + blk] = h[i];
}

// per-bucket exclusive scan over blocks; hmat <- bases, cur <- totals.
__global__ __launch_bounds__(1024) void k_cscan(int* __restrict__ hmat,
                                                int* __restrict__ cur) {
  __shared__ int buf[NPB];
  int b = blockIdx.x, tid = threadIdx.x;
  int v = hmat[(size_t)b * NPB + tid];
  buf[tid] = v;
  __syncthreads();
  for (int off = 1; off < NPB; off <<= 1) {
    int t = (tid >= off) ? buf[tid - off] : 0;
    __syncthreads();
    buf[tid] += t;
    __syncthreads();
  }
  hmat[(size_t)b * NPB + tid] = buf[tid] - v;
  if (tid == NPB - 1) cur[b] = buf[tid];
}

// pass 2: LDS bucket-sort + copy-out at precomputed bases (no global
// atomics). dst stashed in LDS. Entry = (bucket<<24)|((dst&255)<<16)|src.
__global__ __launch_bounds__(256) void k_part2(const int* __restrict__ dst,
                                               const int* __restrict__ src,
                                               const int* __restrict__ hmat,
                                               int* __restrict__ stage, int E) {
  __shared__ int sbuf[PCH];
  __shared__ int dbuf[PCH];
  __shared__ int h[NBK], scn[NBK], base[NBK], lofs[NBK];
  __shared__ int sc[256];
  int tid = threadIdx.x, blk = blockIdx.x;
  for (int i = tid; i < NBK; i += 256) { h[i] = 0; lofs[i] = 0; }
  __syncthreads();
  int b0 = blk * PCH;
  int tot = min(PCH, E - b0);
  for (int k = tid; k < tot; k += 256) {
    int d = dst[b0 + k];
    dbuf[k] = d;
    atomicAdd(&h[d >> 8], 1);
  }
  __syncthreads();
  int v = (tid < NBK) ? h[tid] : 0;
  sc[tid] = v;
  __syncthreads();
  for (int off = 1; off < 256; off <<= 1) {
    int t = (tid >= off) ? sc[tid - off] : 0;
    __syncthreads();
    sc[tid] += t;
    __syncthreads();
  }
  if (tid < NBK) {
    scn[tid] = sc[tid] - v;
    base[tid] = hmat[(size_t)tid * NPB + blk];
  }
  __syncthreads();
  for (int k = tid; k < tot; k += 256) {
    int d = dbuf[k];
    int b = d >> 8;
    int r = atomicAdd(&lofs[b], 1);
    sbuf[scn[b] + r] = (b << 24) | ((d & 255) << 16) | src[b0 + k];
  }
  __syncthreads();
  for (int i = tid; i < tot; i += 256) {
    int e = sbuf[i];
    int b = (unsigned)e >> 24;
    stage[(size_t)b * CAP + base[b] + (i - scn[b])] = e;
  }
}

// per-bucket LDS counting sort: od (int2: cap-strided off, deg) + csr.
__global__ __launch_bounds__(512) void k_build(const int* __restrict__ stage,
                                               const int* __restrict__ tots,
                                               int2* __restrict__ od,
                                               unsigned short* __restrict__ csr,
                                               int n) {
  __shared__ int h[256], buf[256], cur[256];
  int b = blockIdx.x, tid = threadIdx.x;
  int tot = tots[b];
  const int* st = stage + (size_t)b * CAP;
  unsigned short* cs = csr + (size_t)b * CAP;
  if (tid < 256) h[tid] = 0;
  __syncthreads();
  for (int k = tid; k < tot; k += 512)
    atomicAdd(&h[(st[k] >> 16) & 255], 1);
  __syncthreads();
  int v = (tid < 256) ? h[tid] : 0;
  if (tid < 256) buf[tid] = v;
  __syncthreads();
  for (int off = 1; off < 256; off <<= 1) {
    int t = (tid >= off && tid < 256) ? buf[tid - off] : 0;
    __syncthreads();
    if (tid < 256) buf[tid] += t;
    __syncthreads();
  }
  if (tid < 256) {
    int excl = buf[tid] - v;
    int node = b * 256 + tid;
    if (node < n) od[node] = make_int2(b * CAP + excl, v);
    cur[tid] = excl;
  }
  __syncthreads();
  for (int k = tid; k < tot; k += 512) {
    int p = st[k];
    int r = atomicAdd(&cur[(p >> 16) & 255], 1);
    cs[r] = (unsigned short)(p & 0xFFFF);
  }
}

// Pack W1 into MFMA B-fragment order (bf16) + walar = W1@[Ael|Aer] fragments.
__global__ __launch_bounds__(256) void k_packw(const float* __restrict__ W1,
                                               const float* __restrict__ al,
                                               const float* __restrict__ ar,
                                               unsigned short* __restrict__ W1p,
                                               unsigned short* __restrict__ walar) {
  int idx = blockIdx.x * 256 + threadIdx.x;
  if (idx < 8192) {  // W1p
    int nf = idx >> 9, rem = idx & 511;
    int ks = rem >> 6, lane = rem & 63;
    int n = nf * 16 + (lane & 15);
    int kb = ks * 32 + (lane >> 4) * 8;
#pragma unroll
    for (int j = 0; j < 8; ++j)
      W1p[(size_t)idx * 8 + j] = f2bf(W1[(kb + j) * 256 + n]);
  } else if (idx < 8192 + 512) {  // walar: [ks][lane] frag of 256x16
    int idx2 = idx - 8192;
    int ks = idx2 >> 6, lane = idx2 & 63;
    int n = lane & 15;
    int kb = ks * 32 + (lane >> 4) * 8;
    const float* coef = (n < 8) ? (al + n * 32) : (ar + (n - 8) * 32);
    int bc = (n < 8) ? n * 32 : (n - 8) * 32;
#pragma unroll
    for (int j = 0; j < 8; ++j) {
      int k = kb + j;
      float s = 0.f;
      for (int f = 0; f < 32; ++f) s += W1[k * 256 + bc + f] * coef[f];
      walar[(size_t)idx2 * 8 + j] = f2bf(s);
    }
  }
}

// MFMA GEMM, column-split + LDS-staged A: block = 32-row tile converted to
// bf16 in LDS once; wave w handles nf group {4w..4w+3}. Wave 0 adds walar.
__global__ __launch_bounds__(256) void k_gemm1m(
    const float* __restrict__ x, const unsigned short* __restrict__ W1p,
    const unsigned short* __restrict__ walar,
    unsigned char* __restrict__ feat8, float* __restrict__ el,
    float* __restrict__ er, int n) {
  __shared__ unsigned short xs[32][264];  // row stride 528B = 33x16B
  int w = threadIdx.x >> 6, lane = threadIdx.x & 63;
  int tile = blockIdx.x * 32;
  if (tile >= n) return;
  for (int idx = threadIdx.x; idx < 2048; idx += 256) {
    int r = idx >> 6, c4 = (idx & 63) * 4;
    int row = tile + r;
    float4 v = (row < n)
                   ? *reinterpret_cast<const float4*>(x + (size_t)row * 256 + c4)
                   : make_float4(0.f, 0.f, 0.f, 0.f);
    xs[r][c4 + 0] = f2bf(v.x);
    xs[r][c4 + 1] = f2bf(v.y);
    xs[r][c4 + 2] = f2bf(v.z);
    xs[r][c4 + 3] = f2bf(v.w);
  }
  __syncthreads();
  int r0 = lane & 15, kgrp = lane >> 4;
  int nf0 = w * 4;
  f32x4 acc[4][2];
  f32x4 accE[2];
#pragma unroll
  for (int nf = 0; nf < 4; ++nf)
#pragma unroll
    for (int mf = 0; mf < 2; ++mf) acc[nf][mf] = (f32x4){0.f, 0.f, 0.f, 0.f};
  accE[0] = (f32x4){0.f, 0.f, 0.f, 0.f};
  accE[1] = (f32x4){0.f, 0.f, 0.f, 0.f};

  for (int ks = 0; ks < 8; ++ks) {
    int kb = ks * 32 + kgrp * 8;
    short8 a0 = *reinterpret_cast<const short8*>(&xs[r0][kb]);
    short8 a1 = *reinterpret_cast<const short8*>(&xs[16 + r0][kb]);
#pragma unroll
    for (int nf = 0; nf < 4; ++nf) {
      short8 b = *reinterpret_cast<const short8*>(
          W1p + ((size_t)((nf0 + nf) * 8 + ks) * 64 + lane) * 8);
      acc[nf][0] = __builtin_amdgcn_mfma_f32_16x16x32_bf16(a0, b, acc[nf][0], 0, 0, 0);
      acc[nf][1] = __builtin_amdgcn_mfma_f32_16x16x32_bf16(a1, b, acc[nf][1], 0, 0, 0);
    }
    if (w == 0) {
      short8 bE = *reinterpret_cast<const short8*>(
          walar + ((size_t)ks * 64 + lane) * 8);
      accE[0] = __builtin_amdgcn_mfma_f32_16x16x32_bf16(a0, bE, accE[0], 0, 0, 0);
      accE[1] = __builtin_amdgcn_mfma_f32_16x16x32_bf16(a1, bE, accE[1], 0, 0, 0);
    }
  }
  // store feat fp8
#pragma unroll
  for (int nf = 0; nf < 4; ++nf)
#pragma unroll
    for (int mf = 0; mf < 2; ++mf)
#pragma unroll
      for (int q = 0; q < 4; ++q) {
        int row = tile + mf * 16 + kgrp * 4 + q;
        if (row < n)
          feat8[(size_t)row * 256 + (nf0 + nf) * 16 + r0] = f2fp8(acc[nf][mf][q]);
      }
  // store el/er (wave 0): D col c=r0 (c<8 -> el head c, else er head c-8)
  if (w == 0) {
#pragma unroll
    for (int mf = 0; mf < 2; ++mf)
#pragma unroll
      for (int q = 0; q < 4; ++q) {
        int row = tile + mf * 16 + kgrp * 4 + q;
        if (row < n) {
          if (r0 < 8) el[(size_t)row * 8 + r0] = accE[mf][q];
          else        er[(size_t)row * 8 + (r0 - 8)] = accE[mf][q];
        }
      }
  }
}

// Wave per dst node. Lane l owns cols l*4..l*4+3 (head hh=l>>3).
// 8-edge groups: lane (e=l>>3, h=l&7) computes ee once. s via readlane
// (SGPR row base); packed fma on cvt_pk outputs. (off,deg) = one int2 load.
__global__ __launch_bounds__(256) void k_agg1(
    const unsigned char* __restrict__ feat8, const float* __restrict__ el,
    const float* __restrict__ er, const int2* __restrict__ od,
    const unsigned short* __restrict__ csr, const float* __restrict__ b1,
    const float* __restrict__ W2, const float* __restrict__ al2,
    const float* __restrict__ ar2, float4* __restrict__ node4, int n) {
  int dn = blockIdx.x * 4 + (threadIdx.x >> 6);
  if (dn >= n) return;
  int l = threadIdx.x & 63;
  int hh = l >> 3;
  int h8 = l & 7;
  float erv = er[dn * 8 + h8];
  int2 o2 = od[dn];
  int beg = o2.x, end = o2.x + o2.y;
  f32x2 acc01 = {0.f, 0.f}, acc23 = {0.f, 0.f};
  float den = 0.f;
  int g = beg;
  for (; g + 8 <= end; g += 8) {
    int s_my = csr[g + (l >> 3)];
    float eev = lrelu_exp(el[s_my * 8 + h8] + erv);
#pragma unroll
    for (int e = 0; e < 8; ++e) {
      int s = __builtin_amdgcn_readlane(s_my, e * 8);  // uniform -> SGPR
      float ee = __shfl(eev, e * 8 + hh, 64);
      den += ee;
      const unsigned char* rowp = feat8 + (size_t)s * 256;  // scalar base
      unsigned int fv = *reinterpret_cast<const unsigned int*>(rowp + l * 4);
      f32x2 lo = __builtin_amdgcn_cvt_pk_f32_fp8(fv, false);
      f32x2 hi = __builtin_amdgcn_cvt_pk_f32_fp8(fv, true);
      f32x2 ee2 = {ee, ee};
      acc01 = ee2 * lo + acc01;
      acc23 = ee2 * hi + acc23;
    }
  }
  if (g < end) {
    int rem = end - g;
    int idx = g + (l >> 3);
    int s_t = csr[idx < end ? idx : end - 1];
    float ee_t = lrelu_exp(el[s_t * 8 + h8] + erv);
    for (int e = 0; e < rem; ++e) {
      int s = __builtin_amdgcn_readlane(s_t, e * 8);
      float ee = __shfl(ee_t, e * 8 + hh, 64);
      den += ee;
      const unsigned char* rowp = feat8 + (size_t)s * 256;
      unsigned int fv = *reinterpret_cast<const unsigned int*>(rowp + l * 4);
      f32x2 lo = __builtin_amdgcn_cvt_pk_f32_fp8(fv, false);
      f32x2 hi = __builtin_amdgcn_cvt_pk_f32_fp8(fv, true);
      f32x2 ee2 = {ee, ee};
      acc01 = ee2 * lo + acc01;
      acc23 = ee2 * hi + acc23;
    }
  }
  float4 bv = *reinterpret_cast<const float4*>(b1 + l * 4);
  float4 w2e = *reinterpret_cast<const float4*>(W2 + l * 8);
  float4 w2o = *reinterpret_cast<const float4*>(W2 + l * 8 + 4);
  float inv = 1.f / fmaxf(den, 1e-16f);
  float v0 = acc01[0] * inv + bv.x; v0 = v0 > 0.f ? v0 : expm1f(v0);
  float v1 = acc01[1] * inv + bv.y; v1 = v1 > 0.f ? v1 : expm1f(v1);
  float v2 = acc23[0] * inv + bv.z; v2 = v2 > 0.f ? v2 : expm1f(v2);
  float v3 = acc23[1] * inv + bv.w; v3 = v3 > 0.f ? v3 : expm1f(v3);
  float p0 = v0 * w2e.x + v1 * w2e.z + v2 * w2o.x + v3 * w2o.z;
  float p1 = v0 * w2e.y + v1 * w2e.w + v2 * w2o.y + v3 * w2o.w;
#pragma unroll
  for (int off = 32; off; off >>= 1) {
    p0 += __shfl_xor(p0, off, 64);
    p1 += __shfl_xor(p1, off, 64);
  }
  if (l == 0) {
    float e2 = p0 * al2[0] + p1 * al2[1];
    float r2 = p0 * ar2[0] + p1 * ar2[1];
    node4[dn] = make_float4(p0, p1, e2, r2);
  }
}

// 16-lane quarter-wave per node; float4 gather/edge; fused log_softmax.
__global__ __launch_bounds__(256) void k_agg2(
    const float4* __restrict__ node4, const int2* __restrict__ od,
    const unsigned short* __restrict__ csr, const float* __restrict__ b2,
    float* __restrict__ out, int n) {
  int dn = blockIdx.x * 16 + (threadIdx.x >> 4);
  int l = threadIdx.x & 15;
  if (dn >= n) return;
  float erd = node4[dn].w;
  int2 o2 = od[dn];
  int beg = o2.x, end = o2.x + o2.y;
  float den = 0.f, a0 = 0.f, a1 = 0.f;
  for (int e = beg + l; e < end; e += 16) {
    int s = csr[e];
    float4 n4 = node4[s];
    float ev = n4.z + erd;
    ev = ev >= 0.f ? ev : 0.2f * ev;
    float ee = __expf(ev);
    den += ee;
    a0 = fmaf(ee, n4.x, a0);
    a1 = fmaf(ee, n4.y, a1);
  }
#pragma unroll
  for (int off = 8; off; off >>= 1) {
    den += __shfl_xor(den, off, 16);
    a0 += __shfl_xor(a0, off, 16);
    a1 += __shfl_xor(a1, off, 16);
  }
  if (l == 0) {
    float inv = 1.f / fmaxf(den, 1e-16f);
    float z0 = a0 * inv + b2[0];
    float z1 = a1 * inv + b2[1];
    float m = fmaxf(z0, z1);
    float lse = m + logf(__expf(z0 - m) + __expf(z1 - m));
    out[dn * 2 + 0] = z0 - lse;
    out[dn * 2 + 1] = z1 - lse;
  }
}

extern "C" void kernel_launch(void* const* d_in, const int* in_sizes, int n_in,
                              void* d_out, int out_size, void* d_ws,
                              size_t ws_size, hipStream_t stream) {
  const float* x   = (const float*)d_in[0];
  const int* esrc  = (const int*)d_in[1];
  const int* edst  = (const int*)d_in[2];
  const float* W1  = (const float*)d_in[3];
  const float* al1 = (const float*)d_in[4];
  const float* ar1 = (const float*)d_in[5];
  const float* b1  = (const float*)d_in[6];
  const float* W2  = (const float*)d_in[7];
  const float* al2 = (const float*)d_in[8];
  const float* ar2 = (const float*)d_in[9];
  const float* b2  = (const float*)d_in[10];
  float* out = (float*)d_out;

  size_t off = 0;
  auto alloc = [&](size_t bytes) {
    void* p = (char*)d_ws + off;
    off += (bytes + 255) & ~(size_t)255;
    return p;
  };
  unsigned char* feat8 = (unsigned char*)alloc((size_t)NN * 256);
  unsigned short* W1p  = (unsigned short*)alloc((size_t)16 * 8 * 64 * 8 * 2);
  unsigned short* walar = (unsigned short*)alloc((size_t)8 * 64 * 8 * 2);
  float* el1    = (float*)alloc((size_t)NN * 8 * 4);
  float* er1    = (float*)alloc((size_t)NN * 8 * 4);
  float4* node4 = (float4*)alloc((size_t)NN * 16);
  int* stage    = (int*)alloc((size_t)NBK * CAP * 4);
  int* hmat     = (int*)alloc((size_t)NBK * NPB * 4);
  unsigned short* csr = (unsigned short*)alloc((size_t)NBK * CAP * 2);
  int2* od      = (int2*)alloc((size_t)NN * 8);
  int* cur      = (int*)alloc((size_t)NBK * 4);

  k_hist2<<<NPB, 256, 0, stream>>>(edst, hmat, NE);
  k_cscan<<<NBK, NPB, 0, stream>>>(hmat, cur);
  k_part2<<<NPB, 256, 0, stream>>>(edst, esrc, hmat, stage, NE);
  k_build<<<NBK, 512, 0, stream>>>(stage, cur, od, csr, NN);

  k_packw<<<34, 256, 0, stream>>>(W1, al1, ar1, W1p, walar);
  k_gemm1m<<<(NN + 31) / 32, 256, 0, stream>>>(x, W1p, walar, feat8, el1,
                                               er1, NN);
  k_agg1<<<(NN + 3) / 4, 256, 0, stream>>>(feat8, el1, er1, od, csr, b1,
                                           W2, al2, ar2, node4, NN);
  k_agg2<<<(NN + 15) / 16, 256, 0, stream>>>(node4, od, csr, b2, out, NN);
}